// Round 7
// baseline (388.836 us; speedup 1.0000x reference)
//
#include <hip/hip_runtime.h>
#include <hip/hip_bf16.h>

typedef __bf16 bf16x8 __attribute__((ext_vector_type(8)));
typedef __bf16 bf16x4 __attribute__((ext_vector_type(4)));
typedef float  f32x4  __attribute__((ext_vector_type(4)));

#define B_SZ    1024
#define COUT_SZ 512
#define K_SZ    32768   // G * CIN
#define BK 32

// ---------------------------------------------------------------------------
// W fp32 [k][o] -> Wt bf16 [o][k]. 64x64 tiles via fp32 LDS, pitch 65
// (<=2-way banks both phases, verified).
// ---------------------------------------------------------------------------
__global__ __launch_bounds__(256) void wtrans_kernel(
    const float* __restrict__ w, __bf16* __restrict__ wt) {
  __shared__ float t[64 * 65];
  const int kb = (blockIdx.x & 511) * 64;   // K_SZ/64 = 512
  const int ob = (blockIdx.x >> 9) * 64;
  const int tid = threadIdx.x;
  {  // load 64x64 fp32 tile, coalesced 256B rows
    const int o4 = (tid & 15) * 4;
    const int kr = tid >> 4;
    const float* src = w + (size_t)(kb + kr) * COUT_SZ + ob + o4;
#pragma unroll
    for (int i = 0; i < 4; ++i) {
      f32x4 v = *(const f32x4*)(src + (size_t)(16 * i) * COUT_SZ);
      *(f32x4*)&t[(kr + 16 * i) * 65 + o4] = v;
    }
  }
  __syncthreads();
  {  // transposed store, coalesced 128B rows of Wt
    const int k4 = (tid & 15) * 4;
    const int orow = tid >> 4;
#pragma unroll
    for (int j = 0; j < 4; ++j) {
      const int o = orow + 16 * j;
      bf16x4 p;
#pragma unroll
      for (int e = 0; e < 4; ++e) p[e] = (__bf16)t[(k4 + e) * 65 + o];
      *(bf16x4*)(wt + (size_t)(ob + o) * K_SZ + kb + k4) = p;
    }
  }
}

// ---------------------------------------------------------------------------
// Split-K GEMM, LDS-FREE / BARRIER-FREE. Every LDS-staged variant (R1-R6)
// was latency-bound at 60-120us: the load->LDS->barrier chain puts a full
// global-load latency on the per-iter critical path (all utils <15%).
//
// Here each wave owns a 64x64 out-tile and loads A/B fragments DIRECTLY in
// MFMA operand layout (validated by R1-R6's passing feeds):
//   A frag i: lane reads x[m0 + i*16 + lm][k + q*8 .. +8] fp32 -> cvt bf16
//   B frag j: lane reads wt[n0 + w*64 + j*16 + lm][k + q*8 .. +8] bf16
// Block = 4 waves sharing the SAME m-rows (waves differ in n only) -> all
// A lines L1-multicast x4. A line (128B) = exactly one iter's k-chunk; B
// line = two iters -> no over-fetch. 16 independent waves/CU (4 blocks,
// no __syncthreads anywhere) hide each other's VMEM latency (m114).
//
// Block map lin = z + S*t: XCD = z%8 -> z-group co-resident per XCD; per-
// iter working set (x 512KB + wt 32KB per XCD) fits 4MB L2.
// ---------------------------------------------------------------------------
__global__ __launch_bounds__(256, 4)
void gemm_kernel(const float* __restrict__ x, const __bf16* __restrict__ wt,
                 __bf16* __restrict__ dst, int kchunk, int S) {
  const int lin = blockIdx.x;
  const int z = lin % S;
  const int t = lin / S;
  const int m0 = (t & 15) * 64;    // 16 m-tiles of 64
  const int n0 = (t >> 4) * 256;   // 2 n-tiles of 256
  const int w    = (threadIdx.x >> 6);
  const int lane = threadIdx.x & 63;
  const int lm = lane & 15;
  const int q  = lane >> 4;
  const int kbase = z * kchunk;

  // per-lane fragment source pointers (advance BK per iter)
  const float* ap0 = x + (size_t)(m0 + 0 * 16 + lm) * K_SZ + kbase + q * 8;
  const float* ap1 = x + (size_t)(m0 + 1 * 16 + lm) * K_SZ + kbase + q * 8;
  const float* ap2 = x + (size_t)(m0 + 2 * 16 + lm) * K_SZ + kbase + q * 8;
  const float* ap3 = x + (size_t)(m0 + 3 * 16 + lm) * K_SZ + kbase + q * 8;
  const int nb = n0 + w * 64;
  const __bf16* bp0 = wt + (size_t)(nb + 0 * 16 + lm) * K_SZ + kbase + q * 8;
  const __bf16* bp1 = wt + (size_t)(nb + 1 * 16 + lm) * K_SZ + kbase + q * 8;
  const __bf16* bp2 = wt + (size_t)(nb + 2 * 16 + lm) * K_SZ + kbase + q * 8;
  const __bf16* bp3 = wt + (size_t)(nb + 3 * 16 + lm) * K_SZ + kbase + q * 8;

  f32x4 acc[4][4];
#pragma unroll
  for (int i = 0; i < 4; ++i)
#pragma unroll
    for (int j = 0; j < 4; ++j)
      acc[i][j] = (f32x4){0.f, 0.f, 0.f, 0.f};

  const int niter = kchunk / BK;
  for (int it = 0; it < niter; ++it) {
    // issue all 12 loads up front (independent; waitcnt lands at first use)
    f32x4 al0 = *(const f32x4*)ap0, ah0 = *(const f32x4*)(ap0 + 4);
    f32x4 al1 = *(const f32x4*)ap1, ah1 = *(const f32x4*)(ap1 + 4);
    f32x4 al2 = *(const f32x4*)ap2, ah2 = *(const f32x4*)(ap2 + 4);
    f32x4 al3 = *(const f32x4*)ap3, ah3 = *(const f32x4*)(ap3 + 4);
    bf16x8 bv0 = *(const bf16x8*)bp0;
    bf16x8 bv1 = *(const bf16x8*)bp1;
    bf16x8 bv2 = *(const bf16x8*)bp2;
    bf16x8 bv3 = *(const bf16x8*)bp3;
    ap0 += BK; ap1 += BK; ap2 += BK; ap3 += BK;
    bp0 += BK; bp1 += BK; bp2 += BK; bp3 += BK;

    bf16x8 av[4];
#pragma unroll
    for (int e = 0; e < 4; ++e) {
      av[0][e] = (__bf16)al0[e]; av[0][e + 4] = (__bf16)ah0[e];
      av[1][e] = (__bf16)al1[e]; av[1][e + 4] = (__bf16)ah1[e];
      av[2][e] = (__bf16)al2[e]; av[2][e + 4] = (__bf16)ah2[e];
      av[3][e] = (__bf16)al3[e]; av[3][e + 4] = (__bf16)ah3[e];
    }

#pragma unroll
    for (int i = 0; i < 4; ++i) {
      acc[i][0] = __builtin_amdgcn_mfma_f32_16x16x32_bf16(av[i], bv0, acc[i][0], 0, 0, 0);
      acc[i][1] = __builtin_amdgcn_mfma_f32_16x16x32_bf16(av[i], bv1, acc[i][1], 0, 0, 0);
      acc[i][2] = __builtin_amdgcn_mfma_f32_16x16x32_bf16(av[i], bv2, acc[i][2], 0, 0, 0);
      acc[i][3] = __builtin_amdgcn_mfma_f32_16x16x32_bf16(av[i], bv3, acc[i][3], 0, 0, 0);
    }
  }

  // epilogue -> bf16 partials. C/D layout col=lane&15, row=(lane>>4)*4+reg.
  __bf16* outp = dst + (size_t)z * (B_SZ * COUT_SZ)
               + (size_t)(m0 + q * 4) * COUT_SZ + (nb + lm);
#pragma unroll
  for (int i = 0; i < 4; ++i) {
#pragma unroll
    for (int r = 0; r < 4; ++r) {
      __bf16* o2 = outp + (size_t)(i * 16 + r) * COUT_SZ;
#pragma unroll
      for (int j = 0; j < 4; ++j)
        o2[j * 16] = (__bf16)acc[i][j][r];
    }
  }
}

// ---------------------------------------------------------------------------
// Reduce S bf16 partial slices (fp32 accumulate) + scale by 1/sqrt(512).
// ---------------------------------------------------------------------------
__global__ __launch_bounds__(256) void reduce_kernel(
    const __bf16* __restrict__ p, float* __restrict__ out, int S, float scale) {
  const size_t i = ((size_t)blockIdx.x * 256 + threadIdx.x) * 8;
  float s[8];
#pragma unroll
  for (int e = 0; e < 8; ++e) s[e] = 0.f;
  for (int zz = 0; zz < S; ++zz) {
    bf16x8 v = *(const bf16x8*)(p + (size_t)zz * (B_SZ * COUT_SZ) + i);
#pragma unroll
    for (int e = 0; e < 8; ++e) s[e] += (float)v[e];
  }
  f32x4 o0, o1;
#pragma unroll
  for (int e = 0; e < 4; ++e) { o0[e] = s[e] * scale; o1[e] = s[e + 4] * scale; }
  *(f32x4*)(out + i) = o0;
  *(f32x4*)(out + i + 4) = o1;
}

extern "C" void kernel_launch(void* const* d_in, const int* in_sizes, int n_in,
                              void* d_out, int out_size, void* d_ws, size_t ws_size,
                              hipStream_t stream) {
  const float* x = (const float*)d_in[0];
  const float* w = (const float*)d_in[1];
  float* out = (float*)d_out;

  const size_t wtB    = (size_t)COUT_SZ * K_SZ * sizeof(__bf16);   // 33.5 MB
  const size_t sliceB = (size_t)B_SZ * COUT_SZ * sizeof(__bf16);   // 1 MB

  __bf16* wt = (__bf16*)d_ws;
  __bf16* partials = (__bf16*)((char*)d_ws + wtB);

  int S = 32;  // grid 1024 = 4 blocks/CU co-resident; kchunk 1024 (32 iters)
  while (S > 1 && wtB + (size_t)S * sliceB > ws_size) S >>= 1;

  const float scale = 0.04419417382415922f;  // 1/sqrt(512)

  hipLaunchKernelGGL(wtrans_kernel, dim3((K_SZ / 64) * (COUT_SZ / 64)), dim3(256),
                     0, stream, w, wt);
  hipLaunchKernelGGL(gemm_kernel, dim3(32 * S), dim3(256), 0, stream,
                     x, wt, partials, K_SZ / S, S);
  hipLaunchKernelGGL(reduce_kernel, dim3(B_SZ * COUT_SZ / (256 * 8)), dim3(256),
                     0, stream, partials, out, S, scale);
}

// Round 8
// 314.934 us; speedup vs baseline: 1.2347x; 1.2347x over previous
//
#include <hip/hip_runtime.h>
#include <hip/hip_bf16.h>

typedef __bf16 bf16x8 __attribute__((ext_vector_type(8)));
typedef __bf16 bf16x4 __attribute__((ext_vector_type(4)));
typedef float  f32x4  __attribute__((ext_vector_type(4)));

#define B_SZ    1024
#define COUT_SZ 512
#define K_SZ    32768   // G * CIN
#define TM 128
#define TN 128
#define BK 32

// async 16B/lane global -> LDS DMA; lane l lands at base + 16*l.
__device__ __forceinline__ void async_copy16(const void* g, void* l) {
  __builtin_amdgcn_global_load_lds(
      (const __attribute__((address_space(1))) unsigned int*)g,
      (__attribute__((address_space(3))) unsigned int*)l, 16, 0, 0);
}

// ---------------------------------------------------------------------------
// x fp32 -> bf16 (bulk streaming, grid-stride, deep ILP).
// ---------------------------------------------------------------------------
#define XCVT_BLOCKS 2048
__global__ __launch_bounds__(256) void xcvt_kernel(
    const float* __restrict__ x, __bf16* __restrict__ xb) {
  const size_t stride = (size_t)XCVT_BLOCKS * 256 * 8;
  size_t i = ((size_t)blockIdx.x * 256 + threadIdx.x) * 8;
#pragma unroll
  for (int it = 0; it < 4; ++it) {  // 2 chunks/iter -> 8 sweeps total
    f32x4 a0 = *(const f32x4*)(x + i);
    f32x4 c0 = *(const f32x4*)(x + i + 4);
    f32x4 a1 = *(const f32x4*)(x + i + stride);
    f32x4 c1 = *(const f32x4*)(x + i + stride + 4);
    bf16x8 o0, o1;
#pragma unroll
    for (int e = 0; e < 4; ++e) {
      o0[e] = (__bf16)a0[e]; o0[e + 4] = (__bf16)c0[e];
      o1[e] = (__bf16)a1[e]; o1[e + 4] = (__bf16)c1[e];
    }
    *(bf16x8*)(xb + i) = o0;
    *(bf16x8*)(xb + i + stride) = o1;
    i += 2 * stride;
  }
}

// ---------------------------------------------------------------------------
// W fp32 [k][o] -> Wt bf16 [o][k]. 64x64 tiles via fp32 LDS, pitch 65
// (<=2-way banks both phases, verified).
// ---------------------------------------------------------------------------
__global__ __launch_bounds__(256) void wtrans_kernel(
    const float* __restrict__ w, __bf16* __restrict__ wt) {
  __shared__ float t[64 * 65];
  const int kb = (blockIdx.x & 511) * 64;   // K_SZ/64 = 512
  const int ob = (blockIdx.x >> 9) * 64;
  const int tid = threadIdx.x;
  {  // load 64x64 fp32 tile, coalesced 256B rows
    const int o4 = (tid & 15) * 4;
    const int kr = tid >> 4;
    const float* src = w + (size_t)(kb + kr) * COUT_SZ + ob + o4;
#pragma unroll
    for (int i = 0; i < 4; ++i) {
      f32x4 v = *(const f32x4*)(src + (size_t)(16 * i) * COUT_SZ);
      *(f32x4*)&t[(kr + 16 * i) * 65 + o4] = v;
    }
  }
  __syncthreads();
  {  // transposed store, coalesced 128B rows of Wt
    const int k4 = (tid & 15) * 4;
    const int orow = tid >> 4;
#pragma unroll
    for (int j = 0; j < 4; ++j) {
      const int o = orow + 16 * j;
      bf16x4 p;
#pragma unroll
      for (int e = 0; e < 4; ++e) p[e] = (__bf16)t[(k4 + e) * 65 + o];
      *(bf16x4*)(wt + (size_t)(ob + o) * K_SZ + kb + k4) = p;
    }
  }
}

// ---------------------------------------------------------------------------
// Split-K GEMM: m97 tile shape (128x128, 256 thr, 4 waves, 4x4 frags of
// 16x16x32 bf16, BK=32) + DOUBLE-BUFFERED LDS at 4 blocks/CU — the one
// combination untested so far. One barrier per iter:
//   [barrier: drains buf p's DMAs, issued a full compute phase ago]
//   [issue DMAs -> buf p^1]   [compute from buf p]
// The drain stall is latency-minus-compute instead of full latency (R5's
// single-buf), and 4 staggered blocks/CU (m114) cover the residue.
// LDS 2x16KB = 32 KB/block -> 128 KB/CU at 4 blocks ✓.
//
// 16B-chunk XOR swizzle phys = logical ^ (row&3) on both tiles, realized by
// permuting lanes' GLOBAL sources (DMA pins lane->LDS offset).
// Block map lin = z + S*t: XCD = z%8 -> z-group co-resident per XCD; A-line
// reuse x4 (n-tiles) and B-line reuse x8 (m-tiles) through that XCD's L2;
// z-chunks are k-disjoint -> no HBM-level re-fetch.
// ---------------------------------------------------------------------------
__global__ __launch_bounds__(256, 4)
void gemm_kernel(const __bf16* __restrict__ xb, const __bf16* __restrict__ wt,
                 __bf16* __restrict__ dst, int kchunk, int S) {
  __shared__ __bf16 As[2][TM * BK];  // 2 x 8 KB
  __shared__ __bf16 Bs[2][TN * BK];  // 2 x 8 KB

  const int lin = blockIdx.x;
  const int z = lin % S;
  const int t = lin / S;
  const int m0 = (t & 7) * TM;   // 8 m-tiles
  const int n0 = (t >> 3) * TN;  // 4 n-tiles
  const int tid  = threadIdx.x;
  const int w    = tid >> 6;
  const int lane = tid & 63;
  const int kbase = z * kchunk;

  // staging: wave w covers rows [w*32, w*32+32) of both tiles, 2 DMAs each.
  // lane l -> row l>>2, phys chunk l&3, source logical chunk (l&3)^(row&3).
  const int sRow = lane >> 2;
  const int sCh  = (lane & 3) ^ (sRow & 3);
  const __bf16* ag0 = xb + (size_t)(m0 + w * 32 + sRow) * K_SZ + kbase + sCh * 8;
  const __bf16* ag1 = xb + (size_t)(m0 + w * 32 + 16 + sRow) * K_SZ + kbase + sCh * 8;
  const __bf16* bg0 = wt + (size_t)(n0 + w * 32 + sRow) * K_SZ + kbase + sCh * 8;
  const __bf16* bg1 = wt + (size_t)(n0 + w * 32 + 16 + sRow) * K_SZ + kbase + sCh * 8;
  const int aOff0 = (w * 32) * BK;
  const int aOff1 = (w * 32 + 16) * BK;

  // fragment geometry
  const int lm = lane & 15;
  const int q  = lane >> 4;
  const int wm = (w & 1) * 64;
  const int wn = (w >> 1) * 64;
  const int pc = q ^ (lm & 3);

  f32x4 acc[4][4];
#pragma unroll
  for (int i = 0; i < 4; ++i)
#pragma unroll
    for (int j = 0; j < 4; ++j)
      acc[i][j] = (f32x4){0.f, 0.f, 0.f, 0.f};

  // prologue: fill buffer 0
  async_copy16(ag0, &As[0][aOff0]);
  async_copy16(ag1, &As[0][aOff1]);
  async_copy16(bg0, &Bs[0][aOff0]);
  async_copy16(bg1, &Bs[0][aOff1]);
  ag0 += BK; ag1 += BK; bg0 += BK; bg1 += BK;

  const int niter = kchunk / BK;
  for (int it = 0; it < niter; ++it) {
    __syncthreads();  // drains buf p DMAs (issued one full compute ago)
    const int p = it & 1;
    if (it + 1 < niter) {
      const int np = p ^ 1;
      async_copy16(ag0, &As[np][aOff0]);
      async_copy16(ag1, &As[np][aOff1]);
      async_copy16(bg0, &Bs[np][aOff0]);
      async_copy16(bg1, &Bs[np][aOff1]);
      ag0 += BK; ag1 += BK; bg0 += BK; bg1 += BK;
    }

    bf16x8 af[4], bfr[4];
#pragma unroll
    for (int i = 0; i < 4; ++i)
      af[i] = *(const bf16x8*)&As[p][(wm + i * 16 + lm) * BK + pc * 8];
#pragma unroll
    for (int j = 0; j < 4; ++j)
      bfr[j] = *(const bf16x8*)&Bs[p][(wn + j * 16 + lm) * BK + pc * 8];

#pragma unroll
    for (int i = 0; i < 4; ++i)
#pragma unroll
      for (int j = 0; j < 4; ++j)
        acc[i][j] = __builtin_amdgcn_mfma_f32_16x16x32_bf16(af[i], bfr[j], acc[i][j], 0, 0, 0);
  }

  // epilogue -> bf16 partials. C/D layout col=lane&15, row=(lane>>4)*4+reg.
  __bf16* outp = dst + (size_t)z * (B_SZ * COUT_SZ)
               + (size_t)(m0 + wm + q * 4) * COUT_SZ + (n0 + wn + lm);
#pragma unroll
  for (int i = 0; i < 4; ++i) {
#pragma unroll
    for (int r = 0; r < 4; ++r) {
      __bf16* o2 = outp + (size_t)(i * 16 + r) * COUT_SZ;
#pragma unroll
      for (int j = 0; j < 4; ++j)
        o2[j * 16] = (__bf16)acc[i][j][r];
    }
  }
}

// ---------------------------------------------------------------------------
// Reduce S bf16 partial slices (fp32 accumulate) + scale by 1/sqrt(512).
// ---------------------------------------------------------------------------
__global__ __launch_bounds__(256) void reduce_kernel(
    const __bf16* __restrict__ p, float* __restrict__ out, int S, float scale) {
  const size_t i = ((size_t)blockIdx.x * 256 + threadIdx.x) * 8;
  float s[8];
#pragma unroll
  for (int e = 0; e < 8; ++e) s[e] = 0.f;
  for (int zz = 0; zz < S; ++zz) {
    bf16x8 v = *(const bf16x8*)(p + (size_t)zz * (B_SZ * COUT_SZ) + i);
#pragma unroll
    for (int e = 0; e < 8; ++e) s[e] += (float)v[e];
  }
  f32x4 o0, o1;
#pragma unroll
  for (int e = 0; e < 4; ++e) { o0[e] = s[e] * scale; o1[e] = s[e + 4] * scale; }
  *(f32x4*)(out + i) = o0;
  *(f32x4*)(out + i + 4) = o1;
}

extern "C" void kernel_launch(void* const* d_in, const int* in_sizes, int n_in,
                              void* d_out, int out_size, void* d_ws, size_t ws_size,
                              hipStream_t stream) {
  const float* x = (const float*)d_in[0];
  const float* w = (const float*)d_in[1];
  float* out = (float*)d_out;

  const size_t wtB    = (size_t)COUT_SZ * K_SZ * sizeof(__bf16);   // 33.5 MB
  const size_t xbB    = (size_t)B_SZ * K_SZ * sizeof(__bf16);      // 67 MB
  const size_t sliceB = (size_t)B_SZ * COUT_SZ * sizeof(__bf16);   // 1 MB

  __bf16* wt = (__bf16*)d_ws;
  __bf16* xb = (__bf16*)((char*)d_ws + wtB);
  __bf16* partials = (__bf16*)((char*)d_ws + wtB + xbB);

  int S = 32;  // grid 1024 = 4 blocks/CU co-resident; kchunk 1024 (32 iters)
  while (S > 1 && wtB + xbB + (size_t)S * sliceB > ws_size) S >>= 1;

  const float scale = 0.04419417382415922f;  // 1/sqrt(512)

  hipLaunchKernelGGL(xcvt_kernel, dim3(XCVT_BLOCKS), dim3(256), 0, stream, x, xb);
  hipLaunchKernelGGL(wtrans_kernel, dim3((K_SZ / 64) * (COUT_SZ / 64)), dim3(256),
                     0, stream, w, wt);
  hipLaunchKernelGGL(gemm_kernel, dim3(32 * S), dim3(256), 0, stream,
                     xb, wt, partials, K_SZ / S, S);
  hipLaunchKernelGGL(reduce_kernel, dim3(B_SZ * COUT_SZ / (256 * 8)), dim3(256),
                     0, stream, partials, out, S, scale);
}